// Round 7
// baseline (206.089 us; speedup 1.0000x reference)
//
#include <hip/hip_runtime.h>

#define N_NODESC 50000
#define N_EDGESC 800000
#define MAXDEG 64

typedef short bf16x8 __attribute__((ext_vector_type(8)));   // 8 bf16 = 4 VGPRs
typedef short short4v __attribute__((ext_vector_type(4)));  // 8B LDS store
typedef float f32x4  __attribute__((ext_vector_type(4)));

__device__ inline unsigned short f2bf(float f) {            // RNE fp32->bf16
    unsigned u = __float_as_uint(f);
    unsigned r = u + 0x7FFFu + ((u >> 16) & 1u);
    return (unsigned short)(r >> 16);
}
__device__ inline float bf2f(unsigned short h) {
    return __uint_as_float(((unsigned)h) << 16);
}

// ---------------- KW0: init (deg, z) + W prepack + x -> bf16 copy -----------
// 782 blocks. All blocks: zero deg/z and convert a 16-elem chunk of x into
// xb (bf16, 6.4 MB) -- shrinks the k3 gather working set to ~1 XCD L2.
// Blocks 0-3: pack W1r|W1l into bf16 hi/lo MFMA-fragment order pk[ks][quad]
// [o][j] (element (o,ks,quad,j) = W_cat[o][ks*32+quad*8+j]; k<64: W1r else
// W1l) so k3's B-frag loads are coalesced dwordx4 runs.
__global__ void kW0_init_pack(const float* __restrict__ x,
                              const float* __restrict__ W1l, const float* __restrict__ W1r,
                              short* __restrict__ pkhi, short* __restrict__ pklo,
                              unsigned short* __restrict__ xb,
                              int* __restrict__ deg, float* __restrict__ z) {
    int i = blockIdx.x * 256 + threadIdx.x;
    if (i < N_NODESC) deg[i] = 0;
    if (i < 256) z[i] = 0.0f;

    // ---- xb chunk: 16 consecutive floats -> 16 bf16 (two 16B stores) -------
    int base = i * 16;
    if (base < N_NODESC * 64) {          // 3,200,000 divisible by 16
        const float* src = x + base;
        bf16x8 h0, h1;
        #pragma unroll
        for (int j = 0; j < 2; j++) {
            float4 a = *(const float4*)(src + j * 8);
            float4 b = *(const float4*)(src + j * 8 + 4);
            bf16x8& hh = j ? h1 : h0;
            hh[0] = (short)f2bf(a.x); hh[1] = (short)f2bf(a.y);
            hh[2] = (short)f2bf(a.z); hh[3] = (short)f2bf(a.w);
            hh[4] = (short)f2bf(b.x); hh[5] = (short)f2bf(b.y);
            hh[6] = (short)f2bf(b.z); hh[7] = (short)f2bf(b.w);
        }
        *(bf16x8*)(xb + base) = h0;
        *(bf16x8*)(xb + base + 8) = h1;
    }

    if (blockIdx.x < 4) {
        int ks = blockIdx.x;            // 0..3
        int t  = threadIdx.x;           // 256
        int o  = t & 127;
        int h  = t >> 7;                // quads {2h, 2h+1}
        const float* src = (ks < 2) ? (W1r + o * 64 + ks * 32)
                                    : (W1l + o * 64 + (ks - 2) * 32);
        #pragma unroll
        for (int qi = 0; qi < 2; qi++) {
            int q = 2 * h + qi;
            float4 a = *(const float4*)(src + q * 8);
            float4 b = *(const float4*)(src + q * 8 + 4);
            float v[8] = {a.x, a.y, a.z, a.w, b.x, b.y, b.z, b.w};
            bf16x8 hv, lv;
            #pragma unroll
            for (int j = 0; j < 8; j++) {
                unsigned short hh = f2bf(v[j]);
                hv[j] = (short)hh;
                lv[j] = (short)f2bf(v[j] - bf2f(hh));
            }
            int idx = ((ks * 4 + q) * 128 + o) * 8;
            *(bf16x8*)&pkhi[idx] = hv;
            *(bf16x8*)&pklo[idx] = lv;
        }
    }
}

// ---------------- K1: XCD-partitioned padded-bucket CSR build ---------------
// v8: bucket entries are uint16 (src < 50000 < 65536) -> bucket array 6.4 MB,
// halving scattered-store footprint/writeback and downstream bucket reads.
// 2 dst-range groups (ushort slice = 3.2 MB, L2-fit) -> edge rescans 4x->2x.
#define K1_BLOCKS 2048
#define K1_EPB 782   // ceil(800000 / 1024)
__global__ void k1_bucket(const int* __restrict__ ei, int* __restrict__ deg,
                          unsigned short* __restrict__ bucket) {
    int g   = blockIdx.x & 1;
    int idx = blockIdx.x >> 1;
    int lo = g * (N_NODESC / 2), hi = lo + (N_NODESC / 2);
    int e0 = idx * K1_EPB;
    for (int i = threadIdx.x; i < K1_EPB; i += 256) {
        int e = e0 + i;
        if (e < N_EDGESC) {
            int dst = ei[N_EDGESC + e];
            int src = ei[e];
            if (dst >= lo && dst < hi) {
                int slot = atomicAdd(&deg[dst], 1);
                if (slot < MAXDEG) bucket[dst * MAXDEG + slot] = (unsigned short)src;
            }
        }
    }
}

// ---------------- K3: fused gather-mean + 3-term bf16 MFMA + epilogue -------
// v8: gather reads bf16 rows from xb (128 B/row, working set 6.4 MB ~ XCD
// L2) instead of fp32 x (256 B/row, 12.8 MB). Round-6 model: gather was at
// the (outstanding-requests x latency) / L2-miss-path equilibrium; halving
// bytes and roughly halving the L2 miss rate attacks both. Accumulation
// stays fp32 (bf16->f32 = exact <<16); per-node accumulate order unchanged.
// 4 interleaved node-chains per wave in ONE k-loop (was 2x2 serial pairs).
// Self half (x@W1r) still stages full-precision fp32 x -> hi/lo.
// 16x16x32 layouts (m89/m120): A[m=lane&15][k=quad*8+j],
// B[k=quad*8+j][n=lane&15], D[m=quad*4+reg][n=lane&15].
#define K3S 144   // LDS row stride in bf16 elems (128 + 16 pad)
#define K3BLK 32  // nodes per block

__launch_bounds__(512, 4)
__global__ void k3_fused(const float* __restrict__ x, const unsigned short* __restrict__ xb,
                         const int* __restrict__ deg, const unsigned short* __restrict__ bucket,
                         const short* __restrict__ pkhi, const short* __restrict__ pklo,
                         const float* __restrict__ b1l,
                         const float* __restrict__ W2l, const float* __restrict__ W2r,
                         float* __restrict__ s_out, float* __restrict__ t_out) {
    __shared__ __align__(16) short sAhi[K3BLK * K3S];   // 9216 B
    __shared__ __align__(16) short sAlo[K3BLK * K3S];   // 9216 B
    __shared__ float sSp[8][K3BLK], sTp[8][K3BLK];      // 2048 B

    int tid = threadIdx.x;
    int lane = tid & 63;
    int wave = tid >> 6;   // 0..7
    int col = lane & 15;   // c4 for gather, n-col for MFMA
    int quad = lane >> 4;  // g for gather, k-quad for MFMA
    int node0 = blockIdx.x * K3BLK;

    // ---- stage x (cols 0..63): 512 threads x float4 ------------------------
    float4 sv;
    {
        int n = tid >> 4, kc = tid & 15;   // 32 rows x 16 float4-chunks
        int node = node0 + n;
        if (node < N_NODESC) {
            sv = *(const float4*)(x + node * 64 + kc * 4);
        } else {
            sv = make_float4(0.f, 0.f, 0.f, 0.f);
        }
    }
    {
        int n = tid >> 4, kc = tid & 15;
        float v[4] = {sv.x, sv.y, sv.z, sv.w};
        short4v hv, lv;
        #pragma unroll
        for (int j = 0; j < 4; j++) {
            unsigned short h = f2bf(v[j]);
            hv[j] = (short)h;
            lv[j] = (short)f2bf(v[j] - bf2f(h));
        }
        *(short4v*)&sAhi[n * K3S + kc * 4] = hv;
        *(short4v*)&sAlo[n * K3S + kc * 4] = lv;
    }

    // ---- gather-mean agg half (cols 64..127): 4 chains per wave ------------
    {
        int base = node0 + wave * 4;
        int dd[4], cc[4];
        int bb[4];
        #pragma unroll
        for (int c = 0; c < 4; c++) {
            int nd = base + c;
            dd[c] = 0; bb[c] = 0;
            if (nd < N_NODESC) {
                dd[c] = deg[nd];
                bb[c] = (int)bucket[nd * MAXDEG + lane];
            }
        }
        int kmax = 0;
        #pragma unroll
        for (int c = 0; c < 4; c++) { cc[c] = min(dd[c], MAXDEG); kmax = max(kmax, cc[c]); }

        float4 av[4];
        #pragma unroll
        for (int c = 0; c < 4; c++) av[c] = make_float4(0.f, 0.f, 0.f, 0.f);

        for (int k = 0; k < kmax; k += 8) {
            int i0 = k + quad, i1 = k + 4 + quad;
            #pragma unroll
            for (int c = 0; c < 4; c++) {
                int s0 = __shfl(bb[c], i0);
                int s1 = __shfl(bb[c], i1);
                if (i0 < cc[c]) {
                    short4v hv_ = *(const short4v*)(xb + s0 * 64 + col * 4);
                    av[c].x += bf2f((unsigned short)hv_[0]);
                    av[c].y += bf2f((unsigned short)hv_[1]);
                    av[c].z += bf2f((unsigned short)hv_[2]);
                    av[c].w += bf2f((unsigned short)hv_[3]);
                }
                if (i1 < cc[c]) {
                    short4v hv_ = *(const short4v*)(xb + s1 * 64 + col * 4);
                    av[c].x += bf2f((unsigned short)hv_[0]);
                    av[c].y += bf2f((unsigned short)hv_[1]);
                    av[c].z += bf2f((unsigned short)hv_[2]);
                    av[c].w += bf2f((unsigned short)hv_[3]);
                }
            }
        }
        #pragma unroll
        for (int c = 0; c < 4; c++) {
            #pragma unroll
            for (int m = 16; m <= 32; m <<= 1) {
                av[c].x += __shfl_xor(av[c].x, m);
                av[c].y += __shfl_xor(av[c].y, m);
                av[c].z += __shfl_xor(av[c].z, m);
                av[c].w += __shfl_xor(av[c].w, m);
            }
        }
        if (quad == 0) {
            #pragma unroll
            for (int c = 0; c < 4; c++) {
                int nloc = wave * 4 + c;
                float inv = 1.0f / (float)max(dd[c], 1);
                float vv[4] = {av[c].x * inv, av[c].y * inv, av[c].z * inv, av[c].w * inv};
                short4v hv, lv;
                #pragma unroll
                for (int j = 0; j < 4; j++) {
                    unsigned short h = f2bf(vv[j]);
                    hv[j] = (short)h;
                    lv[j] = (short)f2bf(vv[j] - bf2f(h));
                }
                *(short4v*)&sAhi[nloc * K3S + 64 + col * 4] = hv;
                *(short4v*)&sAlo[nloc * K3S + 64 + col * 4] = lv;
            }
        }
    }

    // ---- B fragments: one 16-out strip per wave (o = wave*16 + col) --------
    int o = wave * 16 + col;
    bf16x8 bhi[4], blo[4];
    float bias_r = b1l[o], w2l_r = W2l[o], w2r_r = W2r[o];
    #pragma unroll
    for (int ks = 0; ks < 4; ks++) {
        int idx = ((ks * 4 + quad) * 128 + o) * 8;
        bhi[ks] = *(const bf16x8*)&pkhi[idx];
        blo[ks] = *(const bf16x8*)&pklo[idx];
    }
    __syncthreads();

    // ---- main loop: 4 ksteps x 2 node-tiles x 3 terms ----------------------
    f32x4 acc[2];
    acc[0] = (f32x4)0.f;
    acc[1] = (f32x4)0.f;

    #pragma unroll
    for (int ks = 0; ks < 4; ks++) {
        #pragma unroll
        for (int nt = 0; nt < 2; nt++) {
            int off = (nt * 16 + col) * K3S + ks * 32 + quad * 8;
            bf16x8 ah = *(const bf16x8*)&sAhi[off];
            bf16x8 al = *(const bf16x8*)&sAlo[off];
            acc[nt] = __builtin_amdgcn_mfma_f32_16x16x32_bf16(ah, bhi[ks], acc[nt], 0, 0, 0);
            acc[nt] = __builtin_amdgcn_mfma_f32_16x16x32_bf16(al, bhi[ks], acc[nt], 0, 0, 0);
            acc[nt] = __builtin_amdgcn_mfma_f32_16x16x32_bf16(ah, blo[ks], acc[nt], 0, 0, 0);
        }
    }

    // ---- epilogue: bias+relu+dots; col-lane shfl reduce + per-wave partials -
    #pragma unroll
    for (int nt = 0; nt < 2; nt++) {
        float sp[4], tp[4];
        #pragma unroll
        for (int reg = 0; reg < 4; reg++) {
            float h = fmaxf(acc[nt][reg] + bias_r, 0.f);
            sp[reg] = h * w2l_r;
            tp[reg] = h * w2r_r;
        }
        #pragma unroll
        for (int reg = 0; reg < 4; reg++) {
            #pragma unroll
            for (int m = 1; m <= 8; m <<= 1) {
                sp[reg] += __shfl_xor(sp[reg], m);
                tp[reg] += __shfl_xor(tp[reg], m);
            }
        }
        if (col == 0) {
            int nn = nt * 16 + quad * 4;
            #pragma unroll
            for (int reg = 0; reg < 4; reg++) {
                sSp[wave][nn + reg] = sp[reg];
                sTp[wave][nn + reg] = tp[reg];
            }
        }
    }
    __syncthreads();
    if (tid < K3BLK) {
        int node = node0 + tid;
        if (node < N_NODESC) {
            float ssum = 0.f, tsum = 0.f;
            #pragma unroll
            for (int w = 0; w < 8; w++) { ssum += sSp[w][tid]; tsum += sTp[w][tid]; }
            s_out[node] = ssum;
            t_out[node] = tsum;
        }
    }
}

// ---------------- K4: layer-2 scalar aggregation + relu -> v ----------------
__global__ void k4_layer2(const float* __restrict__ s, const float* __restrict__ t,
                          const int* __restrict__ deg, const unsigned short* __restrict__ bucket,
                          const float* __restrict__ b2l, float* __restrict__ v) {
    int tid = threadIdx.x;
    int lane = tid & 15;
    int node = blockIdx.x * 16 + (tid >> 4);
    int d = deg[node];
    int c = min(d, MAXDEG);
    float sum = 0.f;
    for (int k = lane; k < c; k += 16) sum += s[bucket[node * MAXDEG + k]];
    sum += __shfl_xor(sum, 1);
    sum += __shfl_xor(sum, 2);
    sum += __shfl_xor(sum, 4);
    sum += __shfl_xor(sum, 8);
    if (lane == 0) {
        float h = sum / (float)max(d, 1) + b2l[0] + t[node];
        v[node] = fmaxf(h, 0.f);
    }
}

// ---------------- K5: z_partial = fc1_W @ v (bias deferred to K6) -----------
// (round-2's fused head regressed 10us -> 102us via per-block __threadfence()
//  forcing cross-XCD L2 ordering. Separate k6 launch is strictly cheaper.)
__global__ void k5_fc1(const float* __restrict__ fc1W, const float* __restrict__ v,
                       float* __restrict__ z) {
    int row = blockIdx.x >> 2;
    int part = blockIdx.x & 3;
    const float4* W4 = (const float4*)(fc1W + row * 50000 + part * 12500);
    const float4* v4 = (const float4*)(v + part * 12500);
    float sum = 0.f;
    for (int i = threadIdx.x; i < 3125; i += 256) {
        float4 w = W4[i], a = v4[i];
        sum += w.x * a.x + w.y * a.y + w.z * a.z + w.w * a.w;
    }
    #pragma unroll
    for (int m = 1; m < 64; m <<= 1) sum += __shfl_xor(sum, m);
    __shared__ float red[4];
    if ((threadIdx.x & 63) == 0) red[threadIdx.x >> 6] = sum;
    __syncthreads();
    if (threadIdx.x == 0) atomicAdd(&z[row], red[0] + red[1] + red[2] + red[3]);
}

// ---------------- K6: pred = fc2_W @ (z + fc1_b) + fc2_b --------------------
__global__ void k6_head(const float* __restrict__ z, const float* __restrict__ fc1b,
                        const float* __restrict__ fc2W, const float* __restrict__ fc2b,
                        float* __restrict__ out) {
    int t = threadIdx.x;  // 256 threads
    float val = (z[t] + fc1b[t]) * fc2W[t];
    #pragma unroll
    for (int m = 1; m < 64; m <<= 1) val += __shfl_xor(val, m);
    __shared__ float red[4];
    if ((t & 63) == 0) red[t >> 6] = val;
    __syncthreads();
    if (t == 0) out[0] = red[0] + red[1] + red[2] + red[3] + fc2b[0];
}

extern "C" void kernel_launch(void* const* d_in, const int* in_sizes, int n_in,
                              void* d_out, int out_size, void* d_ws, size_t ws_size,
                              hipStream_t stream) {
    const float* x    = (const float*)d_in[0];
    const int*   ei   = (const int*)d_in[1];   // jax x64 disabled -> int32
    const float* W1l  = (const float*)d_in[2];
    const float* b1l  = (const float*)d_in[3];
    const float* W1r  = (const float*)d_in[4];
    const float* W2l  = (const float*)d_in[5];
    const float* b2l  = (const float*)d_in[6];
    const float* W2r  = (const float*)d_in[7];
    const float* fc1W = (const float*)d_in[8];
    const float* fc1b = (const float*)d_in[9];
    const float* fc2W = (const float*)d_in[10];
    const float* fc2b = (const float*)d_in[11];
    float* out = (float*)d_out;

    // workspace layout (bytes, 512-aligned)
    char* ws = (char*)d_ws;
    int*            deg    = (int*)           (ws + 0);          //   200,000 B
    float*          z      = (float*)         (ws + 200192);     //     1,024 B
    unsigned short* bucket = (unsigned short*)(ws + 201216);     // 6,400,000 B
    unsigned short* xb     = (unsigned short*)(ws + 6601216);    // 6,400,000 B
    float*          s      = (float*)         (ws + 13001216);   //   200,000 B
    float*          t      = (float*)         (ws + 13201216);   //   200,000 B
    float*          v      = (float*)         (ws + 13401216);   //   200,000 B
    short*          pkhi   = (short*)         (ws + 13601280);   //    32,768 B
    short*          pklo   = (short*)         (ws + 13634048);   //    32,768 B
                                                                 // end 13,666,816

    kW0_init_pack<<<782,  256, 0, stream>>>(x, W1l, W1r, pkhi, pklo, xb, deg, z);
    k1_bucket    <<<K1_BLOCKS, 256, 0, stream>>>(ei, deg, bucket);
    k3_fused     <<<1563, 512, 0, stream>>>(x, xb, deg, bucket, pkhi, pklo, b1l, W2l, W2r, s, t);
    k4_layer2    <<<3125, 256, 0, stream>>>(s, t, deg, bucket, b2l, v);
    k5_fc1       <<<1024, 256, 0, stream>>>(fc1W, v, z);
    k6_head      <<<1,    256, 0, stream>>>(z, fc1b, fc2W, fc2b, out);
}

// Round 8
// 205.003 us; speedup vs baseline: 1.0053x; 1.0053x over previous
//
#include <hip/hip_runtime.h>

#define N_NODESC 50000
#define N_EDGESC 800000
#define MAXDEG 64

typedef short bf16x8 __attribute__((ext_vector_type(8)));   // 8 bf16 = 4 VGPRs
typedef short short4v __attribute__((ext_vector_type(4)));  // 8B LDS store
typedef float f32x4  __attribute__((ext_vector_type(4)));

__device__ inline unsigned short f2bf(float f) {            // RNE fp32->bf16
    unsigned u = __float_as_uint(f);
    unsigned r = u + 0x7FFFu + ((u >> 16) & 1u);
    return (unsigned short)(r >> 16);
}
__device__ inline float bf2f(unsigned short h) {
    return __uint_as_float(((unsigned)h) << 16);
}

// ---------------- KW0: init (deg, z) + W prepack + x -> bf16 copy -----------
// 782 blocks. All blocks: zero deg/z and convert a 16-elem chunk of x into
// xb (bf16, 6.4 MB) -- shrinks the k3 gather working set to ~1 XCD L2.
// Blocks 0-3: pack W1r|W1l into bf16 hi/lo MFMA-fragment order pk[ks][quad]
// [o][j] (element (o,ks,quad,j) = W_cat[o][ks*32+quad*8+j]; k<64: W1r else
// W1l) so k3's B-frag loads are coalesced dwordx4 runs.
__global__ void kW0_init_pack(const float* __restrict__ x,
                              const float* __restrict__ W1l, const float* __restrict__ W1r,
                              short* __restrict__ pkhi, short* __restrict__ pklo,
                              unsigned short* __restrict__ xb,
                              int* __restrict__ deg, float* __restrict__ z) {
    int i = blockIdx.x * 256 + threadIdx.x;
    if (i < N_NODESC) deg[i] = 0;
    if (i < 256) z[i] = 0.0f;

    // ---- xb chunk: 16 consecutive floats -> 16 bf16 (two 16B stores) -------
    int base = i * 16;
    if (base < N_NODESC * 64) {          // 3,200,000 divisible by 16
        const float* src = x + base;
        bf16x8 h0, h1;
        #pragma unroll
        for (int j = 0; j < 2; j++) {
            float4 a = *(const float4*)(src + j * 8);
            float4 b = *(const float4*)(src + j * 8 + 4);
            bf16x8& hh = j ? h1 : h0;
            hh[0] = (short)f2bf(a.x); hh[1] = (short)f2bf(a.y);
            hh[2] = (short)f2bf(a.z); hh[3] = (short)f2bf(a.w);
            hh[4] = (short)f2bf(b.x); hh[5] = (short)f2bf(b.y);
            hh[6] = (short)f2bf(b.z); hh[7] = (short)f2bf(b.w);
        }
        *(bf16x8*)(xb + base) = h0;
        *(bf16x8*)(xb + base + 8) = h1;
    }

    if (blockIdx.x < 4) {
        int ks = blockIdx.x;            // 0..3
        int t  = threadIdx.x;           // 256
        int o  = t & 127;
        int h  = t >> 7;                // quads {2h, 2h+1}
        const float* src = (ks < 2) ? (W1r + o * 64 + ks * 32)
                                    : (W1l + o * 64 + (ks - 2) * 32);
        #pragma unroll
        for (int qi = 0; qi < 2; qi++) {
            int q = 2 * h + qi;
            float4 a = *(const float4*)(src + q * 8);
            float4 b = *(const float4*)(src + q * 8 + 4);
            float v[8] = {a.x, a.y, a.z, a.w, b.x, b.y, b.z, b.w};
            bf16x8 hv, lv;
            #pragma unroll
            for (int j = 0; j < 8; j++) {
                unsigned short hh = f2bf(v[j]);
                hv[j] = (short)hh;
                lv[j] = (short)f2bf(v[j] - bf2f(hh));
            }
            int idx = ((ks * 4 + q) * 128 + o) * 8;
            *(bf16x8*)&pkhi[idx] = hv;
            *(bf16x8*)&pklo[idx] = lv;
        }
    }
}

// ---------------- K1: XCD-partitioned padded-bucket CSR build ---------------
// v9: back to 8 dst-range groups riding the round-robin block->XCD mapping
// (g = blockIdx&7): each group's 0.8 MB ushort bucket slice is written from
// exactly ONE XCD's L2. Round-7's 2-group variant spread each group over 4
// non-coherent XCDs -> bucket-line ping-pong (WRITE_SIZE 40 MB, dur 53us).
// The 8x edge rescans are L3-absorbed (round-1: FETCH 25 MB). src load moved
// inside the range test: 7/8 of edge-visits never touch the src half.
#define K1_BLOCKS 2048
#define K1_EPB (N_EDGESC / (K1_BLOCKS / 8))   // 3125 edges per block
__global__ void k1_bucket(const int* __restrict__ ei, int* __restrict__ deg,
                          unsigned short* __restrict__ bucket) {
    int g   = blockIdx.x & 7;
    int idx = blockIdx.x >> 3;
    int lo = g * (N_NODESC / 8), hi = lo + (N_NODESC / 8);
    int e0 = idx * K1_EPB;
    for (int i = threadIdx.x; i < K1_EPB; i += 256) {
        int e = e0 + i;
        int dst = ei[N_EDGESC + e];
        if (dst >= lo && dst < hi) {
            int src = ei[e];
            int slot = atomicAdd(&deg[dst], 1);
            if (slot < MAXDEG) bucket[dst * MAXDEG + slot] = (unsigned short)src;
        }
    }
}

// ---------------- K3: fused gather-mean + 3-term bf16 MFMA + epilogue -------
// v8: gather reads bf16 rows from xb (128 B/row, working set 6.4 MB ~ XCD
// L2) instead of fp32 x (256 B/row, 12.8 MB). Accumulation stays fp32
// (bf16->f32 = exact <<16); per-node accumulate order unchanged.
// 4 interleaved node-chains per wave in ONE k-loop. Self half (x@W1r)
// still stages full-precision fp32 x -> hi/lo.
// 16x16x32 layouts (m89/m120): A[m=lane&15][k=quad*8+j],
// B[k=quad*8+j][n=lane&15], D[m=quad*4+reg][n=lane&15].
#define K3S 144   // LDS row stride in bf16 elems (128 + 16 pad)
#define K3BLK 32  // nodes per block

__launch_bounds__(512, 4)
__global__ void k3_fused(const float* __restrict__ x, const unsigned short* __restrict__ xb,
                         const int* __restrict__ deg, const unsigned short* __restrict__ bucket,
                         const short* __restrict__ pkhi, const short* __restrict__ pklo,
                         const float* __restrict__ b1l,
                         const float* __restrict__ W2l, const float* __restrict__ W2r,
                         float* __restrict__ s_out, float* __restrict__ t_out) {
    __shared__ __align__(16) short sAhi[K3BLK * K3S];   // 9216 B
    __shared__ __align__(16) short sAlo[K3BLK * K3S];   // 9216 B
    __shared__ float sSp[8][K3BLK], sTp[8][K3BLK];      // 2048 B

    int tid = threadIdx.x;
    int lane = tid & 63;
    int wave = tid >> 6;   // 0..7
    int col = lane & 15;   // c4 for gather, n-col for MFMA
    int quad = lane >> 4;  // g for gather, k-quad for MFMA
    int node0 = blockIdx.x * K3BLK;

    // ---- stage x (cols 0..63): 512 threads x float4 ------------------------
    float4 sv;
    {
        int n = tid >> 4, kc = tid & 15;   // 32 rows x 16 float4-chunks
        int node = node0 + n;
        if (node < N_NODESC) {
            sv = *(const float4*)(x + node * 64 + kc * 4);
        } else {
            sv = make_float4(0.f, 0.f, 0.f, 0.f);
        }
    }
    {
        int n = tid >> 4, kc = tid & 15;
        float v[4] = {sv.x, sv.y, sv.z, sv.w};
        short4v hv, lv;
        #pragma unroll
        for (int j = 0; j < 4; j++) {
            unsigned short h = f2bf(v[j]);
            hv[j] = (short)h;
            lv[j] = (short)f2bf(v[j] - bf2f(h));
        }
        *(short4v*)&sAhi[n * K3S + kc * 4] = hv;
        *(short4v*)&sAlo[n * K3S + kc * 4] = lv;
    }

    // ---- gather-mean agg half (cols 64..127): 4 chains per wave ------------
    {
        int base = node0 + wave * 4;
        int dd[4], cc[4];
        int bb[4];
        #pragma unroll
        for (int c = 0; c < 4; c++) {
            int nd = base + c;
            dd[c] = 0; bb[c] = 0;
            if (nd < N_NODESC) {
                dd[c] = deg[nd];
                bb[c] = (int)bucket[nd * MAXDEG + lane];
            }
        }
        int kmax = 0;
        #pragma unroll
        for (int c = 0; c < 4; c++) { cc[c] = min(dd[c], MAXDEG); kmax = max(kmax, cc[c]); }

        float4 av[4];
        #pragma unroll
        for (int c = 0; c < 4; c++) av[c] = make_float4(0.f, 0.f, 0.f, 0.f);

        for (int k = 0; k < kmax; k += 8) {
            int i0 = k + quad, i1 = k + 4 + quad;
            #pragma unroll
            for (int c = 0; c < 4; c++) {
                int s0 = __shfl(bb[c], i0);
                int s1 = __shfl(bb[c], i1);
                if (i0 < cc[c]) {
                    short4v hv_ = *(const short4v*)(xb + s0 * 64 + col * 4);
                    av[c].x += bf2f((unsigned short)hv_[0]);
                    av[c].y += bf2f((unsigned short)hv_[1]);
                    av[c].z += bf2f((unsigned short)hv_[2]);
                    av[c].w += bf2f((unsigned short)hv_[3]);
                }
                if (i1 < cc[c]) {
                    short4v hv_ = *(const short4v*)(xb + s1 * 64 + col * 4);
                    av[c].x += bf2f((unsigned short)hv_[0]);
                    av[c].y += bf2f((unsigned short)hv_[1]);
                    av[c].z += bf2f((unsigned short)hv_[2]);
                    av[c].w += bf2f((unsigned short)hv_[3]);
                }
            }
        }
        #pragma unroll
        for (int c = 0; c < 4; c++) {
            #pragma unroll
            for (int m = 16; m <= 32; m <<= 1) {
                av[c].x += __shfl_xor(av[c].x, m);
                av[c].y += __shfl_xor(av[c].y, m);
                av[c].z += __shfl_xor(av[c].z, m);
                av[c].w += __shfl_xor(av[c].w, m);
            }
        }
        if (quad == 0) {
            #pragma unroll
            for (int c = 0; c < 4; c++) {
                int nloc = wave * 4 + c;
                float inv = 1.0f / (float)max(dd[c], 1);
                float vv[4] = {av[c].x * inv, av[c].y * inv, av[c].z * inv, av[c].w * inv};
                short4v hv, lv;
                #pragma unroll
                for (int j = 0; j < 4; j++) {
                    unsigned short h = f2bf(vv[j]);
                    hv[j] = (short)h;
                    lv[j] = (short)f2bf(vv[j] - bf2f(h));
                }
                *(short4v*)&sAhi[nloc * K3S + 64 + col * 4] = hv;
                *(short4v*)&sAlo[nloc * K3S + 64 + col * 4] = lv;
            }
        }
    }

    // ---- B fragments: one 16-out strip per wave (o = wave*16 + col) --------
    int o = wave * 16 + col;
    bf16x8 bhi[4], blo[4];
    float bias_r = b1l[o], w2l_r = W2l[o], w2r_r = W2r[o];
    #pragma unroll
    for (int ks = 0; ks < 4; ks++) {
        int idx = ((ks * 4 + quad) * 128 + o) * 8;
        bhi[ks] = *(const bf16x8*)&pkhi[idx];
        blo[ks] = *(const bf16x8*)&pklo[idx];
    }
    __syncthreads();

    // ---- main loop: 4 ksteps x 2 node-tiles x 3 terms ----------------------
    f32x4 acc[2];
    acc[0] = (f32x4)0.f;
    acc[1] = (f32x4)0.f;

    #pragma unroll
    for (int ks = 0; ks < 4; ks++) {
        #pragma unroll
        for (int nt = 0; nt < 2; nt++) {
            int off = (nt * 16 + col) * K3S + ks * 32 + quad * 8;
            bf16x8 ah = *(const bf16x8*)&sAhi[off];
            bf16x8 al = *(const bf16x8*)&sAlo[off];
            acc[nt] = __builtin_amdgcn_mfma_f32_16x16x32_bf16(ah, bhi[ks], acc[nt], 0, 0, 0);
            acc[nt] = __builtin_amdgcn_mfma_f32_16x16x32_bf16(al, bhi[ks], acc[nt], 0, 0, 0);
            acc[nt] = __builtin_amdgcn_mfma_f32_16x16x32_bf16(ah, blo[ks], acc[nt], 0, 0, 0);
        }
    }

    // ---- epilogue: bias+relu+dots; col-lane shfl reduce + per-wave partials -
    #pragma unroll
    for (int nt = 0; nt < 2; nt++) {
        float sp[4], tp[4];
        #pragma unroll
        for (int reg = 0; reg < 4; reg++) {
            float h = fmaxf(acc[nt][reg] + bias_r, 0.f);
            sp[reg] = h * w2l_r;
            tp[reg] = h * w2r_r;
        }
        #pragma unroll
        for (int reg = 0; reg < 4; reg++) {
            #pragma unroll
            for (int m = 1; m <= 8; m <<= 1) {
                sp[reg] += __shfl_xor(sp[reg], m);
                tp[reg] += __shfl_xor(tp[reg], m);
            }
        }
        if (col == 0) {
            int nn = nt * 16 + quad * 4;
            #pragma unroll
            for (int reg = 0; reg < 4; reg++) {
                sSp[wave][nn + reg] = sp[reg];
                sTp[wave][nn + reg] = tp[reg];
            }
        }
    }
    __syncthreads();
    if (tid < K3BLK) {
        int node = node0 + tid;
        if (node < N_NODESC) {
            float ssum = 0.f, tsum = 0.f;
            #pragma unroll
            for (int w = 0; w < 8; w++) { ssum += sSp[w][tid]; tsum += sTp[w][tid]; }
            s_out[node] = ssum;
            t_out[node] = tsum;
        }
    }
}

// ---------------- K4: layer-2 scalar aggregation + relu -> v ----------------
__global__ void k4_layer2(const float* __restrict__ s, const float* __restrict__ t,
                          const int* __restrict__ deg, const unsigned short* __restrict__ bucket,
                          const float* __restrict__ b2l, float* __restrict__ v) {
    int tid = threadIdx.x;
    int lane = tid & 15;
    int node = blockIdx.x * 16 + (tid >> 4);
    int d = deg[node];
    int c = min(d, MAXDEG);
    float sum = 0.f;
    for (int k = lane; k < c; k += 16) sum += s[bucket[node * MAXDEG + k]];
    sum += __shfl_xor(sum, 1);
    sum += __shfl_xor(sum, 2);
    sum += __shfl_xor(sum, 4);
    sum += __shfl_xor(sum, 8);
    if (lane == 0) {
        float h = sum / (float)max(d, 1) + b2l[0] + t[node];
        v[node] = fmaxf(h, 0.f);
    }
}

// ---------------- K5: z_partial = fc1_W @ v (bias deferred to K6) -----------
// (round-2's fused head regressed 10us -> 102us via per-block __threadfence()
//  forcing cross-XCD L2 ordering. Separate k6 launch is strictly cheaper.)
__global__ void k5_fc1(const float* __restrict__ fc1W, const float* __restrict__ v,
                       float* __restrict__ z) {
    int row = blockIdx.x >> 2;
    int part = blockIdx.x & 3;
    const float4* W4 = (const float4*)(fc1W + row * 50000 + part * 12500);
    const float4* v4 = (const float4*)(v + part * 12500);
    float sum = 0.f;
    for (int i = threadIdx.x; i < 3125; i += 256) {
        float4 w = W4[i], a = v4[i];
        sum += w.x * a.x + w.y * a.y + w.z * a.z + w.w * a.w;
    }
    #pragma unroll
    for (int m = 1; m < 64; m <<= 1) sum += __shfl_xor(sum, m);
    __shared__ float red[4];
    if ((threadIdx.x & 63) == 0) red[threadIdx.x >> 6] = sum;
    __syncthreads();
    if (threadIdx.x == 0) atomicAdd(&z[row], red[0] + red[1] + red[2] + red[3]);
}

// ---------------- K6: pred = fc2_W @ (z + fc1_b) + fc2_b --------------------
__global__ void k6_head(const float* __restrict__ z, const float* __restrict__ fc1b,
                        const float* __restrict__ fc2W, const float* __restrict__ fc2b,
                        float* __restrict__ out) {
    int t = threadIdx.x;  // 256 threads
    float val = (z[t] + fc1b[t]) * fc2W[t];
    #pragma unroll
    for (int m = 1; m < 64; m <<= 1) val += __shfl_xor(val, m);
    __shared__ float red[4];
    if ((t & 63) == 0) red[t >> 6] = val;
    __syncthreads();
    if (t == 0) out[0] = red[0] + red[1] + red[2] + red[3] + fc2b[0];
}

extern "C" void kernel_launch(void* const* d_in, const int* in_sizes, int n_in,
                              void* d_out, int out_size, void* d_ws, size_t ws_size,
                              hipStream_t stream) {
    const float* x    = (const float*)d_in[0];
    const int*   ei   = (const int*)d_in[1];   // jax x64 disabled -> int32
    const float* W1l  = (const float*)d_in[2];
    const float* b1l  = (const float*)d_in[3];
    const float* W1r  = (const float*)d_in[4];
    const float* W2l  = (const float*)d_in[5];
    const float* b2l  = (const float*)d_in[6];
    const float* W2r  = (const float*)d_in[7];
    const float* fc1W = (const float*)d_in[8];
    const float* fc1b = (const float*)d_in[9];
    const float* fc2W = (const float*)d_in[10];
    const float* fc2b = (const float*)d_in[11];
    float* out = (float*)d_out;

    // workspace layout (bytes, 512-aligned)
    char* ws = (char*)d_ws;
    int*            deg    = (int*)           (ws + 0);          //   200,000 B
    float*          z      = (float*)         (ws + 200192);     //     1,024 B
    unsigned short* bucket = (unsigned short*)(ws + 201216);     // 6,400,000 B
    unsigned short* xb     = (unsigned short*)(ws + 6601216);    // 6,400,000 B
    float*          s      = (float*)         (ws + 13001216);   //   200,000 B
    float*          t      = (float*)         (ws + 13201216);   //   200,000 B
    float*          v      = (float*)         (ws + 13401216);   //   200,000 B
    short*          pkhi   = (short*)         (ws + 13601280);   //    32,768 B
    short*          pklo   = (short*)         (ws + 13634048);   //    32,768 B
                                                                 // end 13,666,816

    kW0_init_pack<<<782,  256, 0, stream>>>(x, W1l, W1r, pkhi, pklo, xb, deg, z);
    k1_bucket    <<<K1_BLOCKS, 256, 0, stream>>>(ei, deg, bucket);
    k3_fused     <<<1563, 512, 0, stream>>>(x, xb, deg, bucket, pkhi, pklo, b1l, W2l, W2r, s, t);
    k4_layer2    <<<3125, 256, 0, stream>>>(s, t, deg, bucket, b2l, v);
    k5_fc1       <<<1024, 256, 0, stream>>>(fc1W, v, z);
    k6_head      <<<1,    256, 0, stream>>>(z, fc1b, fc2W, fc2b, out);
}

// Round 9
// 203.842 us; speedup vs baseline: 1.0110x; 1.0057x over previous
//
#include <hip/hip_runtime.h>

#define N_NODESC 50000
#define N_EDGESC 800000
#define MAXDEG 64

typedef short bf16x8 __attribute__((ext_vector_type(8)));   // 8 bf16 = 4 VGPRs
typedef short short4v __attribute__((ext_vector_type(4)));  // 8B LDS store
typedef unsigned short ushort4v __attribute__((ext_vector_type(4)));
typedef float f32x4  __attribute__((ext_vector_type(4)));

__device__ inline unsigned short f2bf(float f) {            // RNE fp32->bf16
    unsigned u = __float_as_uint(f);
    unsigned r = u + 0x7FFFu + ((u >> 16) & 1u);
    return (unsigned short)(r >> 16);
}
__device__ inline float bf2f(unsigned short h) {
    return __uint_as_float(((unsigned)h) << 16);
}

// ---------------- KW0: init (deg, z) + W prepack + x -> bf16 copy -----------
// 782 blocks. All blocks: zero deg/z and convert a 16-elem chunk of x into
// xb (bf16, 6.4 MB). Blocks 0-3: pack W1r|W1l into bf16 hi/lo MFMA-fragment
// order pk[ks][quad][o][j] (element (o,ks,quad,j) = W_cat[o][ks*32+quad*8+j];
// k<64: W1r else W1l) so k3's B-frag loads are coalesced dwordx4 runs.
__global__ void kW0_init_pack(const float* __restrict__ x,
                              const float* __restrict__ W1l, const float* __restrict__ W1r,
                              short* __restrict__ pkhi, short* __restrict__ pklo,
                              unsigned short* __restrict__ xb,
                              int* __restrict__ deg, float* __restrict__ z) {
    int i = blockIdx.x * 256 + threadIdx.x;
    if (i < N_NODESC) deg[i] = 0;
    if (i < 256) z[i] = 0.0f;

    // ---- xb chunk: 16 consecutive floats -> 16 bf16 (two 16B stores) -------
    int base = i * 16;
    if (base < N_NODESC * 64) {          // 3,200,000 divisible by 16
        const float* src = x + base;
        bf16x8 h0, h1;
        #pragma unroll
        for (int j = 0; j < 2; j++) {
            float4 a = *(const float4*)(src + j * 8);
            float4 b = *(const float4*)(src + j * 8 + 4);
            bf16x8& hh = j ? h1 : h0;
            hh[0] = (short)f2bf(a.x); hh[1] = (short)f2bf(a.y);
            hh[2] = (short)f2bf(a.z); hh[3] = (short)f2bf(a.w);
            hh[4] = (short)f2bf(b.x); hh[5] = (short)f2bf(b.y);
            hh[6] = (short)f2bf(b.z); hh[7] = (short)f2bf(b.w);
        }
        *(bf16x8*)(xb + base) = h0;
        *(bf16x8*)(xb + base + 8) = h1;
    }

    if (blockIdx.x < 4) {
        int ks = blockIdx.x;            // 0..3
        int t  = threadIdx.x;           // 256
        int o  = t & 127;
        int h  = t >> 7;                // quads {2h, 2h+1}
        const float* src = (ks < 2) ? (W1r + o * 64 + ks * 32)
                                    : (W1l + o * 64 + (ks - 2) * 32);
        #pragma unroll
        for (int qi = 0; qi < 2; qi++) {
            int q = 2 * h + qi;
            float4 a = *(const float4*)(src + q * 8);
            float4 b = *(const float4*)(src + q * 8 + 4);
            float v[8] = {a.x, a.y, a.z, a.w, b.x, b.y, b.z, b.w};
            bf16x8 hv, lv;
            #pragma unroll
            for (int j = 0; j < 8; j++) {
                unsigned short hh = f2bf(v[j]);
                hv[j] = (short)hh;
                lv[j] = (short)f2bf(v[j] - bf2f(hh));
            }
            int idx = ((ks * 4 + q) * 128 + o) * 8;
            *(bf16x8*)&pkhi[idx] = hv;
            *(bf16x8*)&pklo[idx] = lv;
        }
    }
}

// ---------------- K1: XCD-partitioned padded-bucket CSR build ---------------
// 8 dst-range groups riding the round-robin block->XCD mapping (g=blockIdx&7)
// so each group's 0.8 MB ushort bucket slice is written from ONE XCD's L2.
// (2/4-group variants ping-pong bucket lines across non-coherent L2s: +13us.)
#define K1_BLOCKS 2048
#define K1_EPB (N_EDGESC / (K1_BLOCKS / 8))   // 3125 edges per block
__global__ void k1_bucket(const int* __restrict__ ei, int* __restrict__ deg,
                          unsigned short* __restrict__ bucket) {
    int g   = blockIdx.x & 7;
    int idx = blockIdx.x >> 3;
    int lo = g * (N_NODESC / 8), hi = lo + (N_NODESC / 8);
    int e0 = idx * K1_EPB;
    for (int i = threadIdx.x; i < K1_EPB; i += 256) {
        int e = e0 + i;
        int dst = ei[N_EDGESC + e];
        if (dst >= lo && dst < hi) {
            int src = ei[e];
            int slot = atomicAdd(&deg[dst], 1);
            if (slot < MAXDEG) bucket[dst * MAXDEG + slot] = (unsigned short)src;
        }
    }
}

// ---------------- K3: fused gather-mean + 3-term bf16 MFMA + epilogue -------
// v9: FEATURE-PER-LANE gather. Round-8 showed the old quad-chain gather was
// latency-glue-bound (FETCH halved 83->37 MB, dur unchanged 42.5us; all pipes
// <30%): ds_bpermute->vmem serial chains, divergence guards, 8-op shfl
// reduction trees. New scheme: stage the block's 32 bucket rows (4 KB,
// contiguous) + deg into LDS once; per wave per node, loop j<deg with
// WAVE-UNIFORM index reads (ds_read_b64 = 4 idx, broadcast, conflict-free)
// and av[lane] += bf2f(xb[idx*64+lane]) -- coalesced 128B wave-loads, 8
// independent accumulators, zero bpermute, zero cross-lane reduce, zero
// divergence. Association changes (slot-strided); fp32 accum, within budget.
// 16x16x32 layouts (m89/m120): A[m=lane&15][k=quad*8+j],
// B[k=quad*8+j][n=lane&15], D[m=quad*4+reg][n=lane&15].
#define K3S 144   // LDS row stride in bf16 elems (128 + 16 pad)
#define K3BLK 32  // nodes per block

__launch_bounds__(512, 4)
__global__ void k3_fused(const float* __restrict__ x, const unsigned short* __restrict__ xb,
                         const int* __restrict__ deg, const unsigned short* __restrict__ bucket,
                         const short* __restrict__ pkhi, const short* __restrict__ pklo,
                         const float* __restrict__ b1l,
                         const float* __restrict__ W2l, const float* __restrict__ W2r,
                         float* __restrict__ s_out, float* __restrict__ t_out) {
    __shared__ __align__(16) short sAhi[K3BLK * K3S];        // 9216 B
    __shared__ __align__(16) short sAlo[K3BLK * K3S];        // 9216 B
    __shared__ __align__(16) unsigned short sBkt[K3BLK * 64];// 4096 B
    __shared__ int sDeg[K3BLK];                              //  128 B
    __shared__ float sSp[8][K3BLK], sTp[8][K3BLK];           // 2048 B

    int tid = threadIdx.x;
    int lane = tid & 63;
    int wave = tid >> 6;   // 0..7
    int col = lane & 15;   // n-col for MFMA
    int quad = lane >> 4;  // k-quad for MFMA
    int node0 = blockIdx.x * K3BLK;

    // ---- stage x (cols 0..63): 512 threads x float4 ------------------------
    float4 sv;
    {
        int n = tid >> 4, kc = tid & 15;   // 32 rows x 16 float4-chunks
        int node = node0 + n;
        if (node < N_NODESC) {
            sv = *(const float4*)(x + node * 64 + kc * 4);
        } else {
            sv = make_float4(0.f, 0.f, 0.f, 0.f);
        }
    }

    // ---- stage bucket rows (contiguous 4 KB) + deg into LDS ----------------
    {
        int off = tid * 4;                          // 0..2044
        int glim = (N_NODESC - node0) * 64;         // elems available
        if (off + 4 <= glim) {
            *(ushort4v*)&sBkt[off] = *(const ushort4v*)&bucket[node0 * 64 + off];
        } else {
            #pragma unroll
            for (int k = 0; k < 4; k++)
                sBkt[off + k] = (off + k < glim) ? bucket[node0 * 64 + off + k]
                                                 : (unsigned short)0;
        }
        if (tid < K3BLK) {
            int node = node0 + tid;
            sDeg[tid] = (node < N_NODESC) ? deg[node] : 0;
        }
    }

    // ---- convert staged x to bf16 hi/lo, write LDS cols 0..63 --------------
    {
        int n = tid >> 4, kc = tid & 15;
        float v[4] = {sv.x, sv.y, sv.z, sv.w};
        short4v hv, lv;
        #pragma unroll
        for (int j = 0; j < 4; j++) {
            unsigned short h = f2bf(v[j]);
            hv[j] = (short)h;
            lv[j] = (short)f2bf(v[j] - bf2f(h));
        }
        *(short4v*)&sAhi[n * K3S + kc * 4] = hv;
        *(short4v*)&sAlo[n * K3S + kc * 4] = lv;
    }
    __syncthreads();   // sBkt/sDeg ready for gather

    // ---- gather-mean agg half (cols 64..127): feature-per-lane -------------
    #pragma unroll
    for (int c4 = 0; c4 < 4; c4++) {
        int nloc = wave * 4 + c4;
        int d = sDeg[nloc];
        int c = min(d, MAXDEG);
        float a0 = 0.f, a1 = 0.f, a2 = 0.f, a3 = 0.f;
        float a4 = 0.f, a5 = 0.f, a6 = 0.f, a7 = 0.f;
        int j = 0;
        for (; j + 8 <= c; j += 8) {
            ushort4v q0 = *(const ushort4v*)&sBkt[nloc * 64 + j];
            ushort4v q1 = *(const ushort4v*)&sBkt[nloc * 64 + j + 4];
            a0 += bf2f(xb[(int)q0[0] * 64 + lane]);
            a1 += bf2f(xb[(int)q0[1] * 64 + lane]);
            a2 += bf2f(xb[(int)q0[2] * 64 + lane]);
            a3 += bf2f(xb[(int)q0[3] * 64 + lane]);
            a4 += bf2f(xb[(int)q1[0] * 64 + lane]);
            a5 += bf2f(xb[(int)q1[1] * 64 + lane]);
            a6 += bf2f(xb[(int)q1[2] * 64 + lane]);
            a7 += bf2f(xb[(int)q1[3] * 64 + lane]);
        }
        for (; j < c; j++) {
            a0 += bf2f(xb[(int)sBkt[nloc * 64 + j] * 64 + lane]);
        }
        float av = ((a0 + a1) + (a2 + a3)) + ((a4 + a5) + (a6 + a7));
        float inv = 1.0f / (float)max(d, 1);
        float m = av * inv;
        unsigned short h = f2bf(m);
        unsigned short l = f2bf(m - bf2f(h));
        sAhi[nloc * K3S + 64 + lane] = (short)h;
        sAlo[nloc * K3S + 64 + lane] = (short)l;
    }

    // ---- B fragments: one 16-out strip per wave (o = wave*16 + col) --------
    int o = wave * 16 + col;
    bf16x8 bhi[4], blo[4];
    float bias_r = b1l[o], w2l_r = W2l[o], w2r_r = W2r[o];
    #pragma unroll
    for (int ks = 0; ks < 4; ks++) {
        int idx = ((ks * 4 + quad) * 128 + o) * 8;
        bhi[ks] = *(const bf16x8*)&pkhi[idx];
        blo[ks] = *(const bf16x8*)&pklo[idx];
    }
    __syncthreads();

    // ---- main loop: 4 ksteps x 2 node-tiles x 3 terms ----------------------
    f32x4 acc[2];
    acc[0] = (f32x4)0.f;
    acc[1] = (f32x4)0.f;

    #pragma unroll
    for (int ks = 0; ks < 4; ks++) {
        #pragma unroll
        for (int nt = 0; nt < 2; nt++) {
            int off = (nt * 16 + col) * K3S + ks * 32 + quad * 8;
            bf16x8 ah = *(const bf16x8*)&sAhi[off];
            bf16x8 al = *(const bf16x8*)&sAlo[off];
            acc[nt] = __builtin_amdgcn_mfma_f32_16x16x32_bf16(ah, bhi[ks], acc[nt], 0, 0, 0);
            acc[nt] = __builtin_amdgcn_mfma_f32_16x16x32_bf16(al, bhi[ks], acc[nt], 0, 0, 0);
            acc[nt] = __builtin_amdgcn_mfma_f32_16x16x32_bf16(ah, blo[ks], acc[nt], 0, 0, 0);
        }
    }

    // ---- epilogue: bias+relu+dots; col-lane shfl reduce + per-wave partials -
    #pragma unroll
    for (int nt = 0; nt < 2; nt++) {
        float sp[4], tp[4];
        #pragma unroll
        for (int reg = 0; reg < 4; reg++) {
            float h = fmaxf(acc[nt][reg] + bias_r, 0.f);
            sp[reg] = h * w2l_r;
            tp[reg] = h * w2r_r;
        }
        #pragma unroll
        for (int reg = 0; reg < 4; reg++) {
            #pragma unroll
            for (int m = 1; m <= 8; m <<= 1) {
                sp[reg] += __shfl_xor(sp[reg], m);
                tp[reg] += __shfl_xor(tp[reg], m);
            }
        }
        if (col == 0) {
            int nn = nt * 16 + quad * 4;
            #pragma unroll
            for (int reg = 0; reg < 4; reg++) {
                sSp[wave][nn + reg] = sp[reg];
                sTp[wave][nn + reg] = tp[reg];
            }
        }
    }
    __syncthreads();
    if (tid < K3BLK) {
        int node = node0 + tid;
        if (node < N_NODESC) {
            float ssum = 0.f, tsum = 0.f;
            #pragma unroll
            for (int w = 0; w < 8; w++) { ssum += sSp[w][tid]; tsum += sTp[w][tid]; }
            s_out[node] = ssum;
            t_out[node] = tsum;
        }
    }
}

// ---------------- K4: layer-2 scalar aggregation + relu -> v ----------------
__global__ void k4_layer2(const float* __restrict__ s, const float* __restrict__ t,
                          const int* __restrict__ deg, const unsigned short* __restrict__ bucket,
                          const float* __restrict__ b2l, float* __restrict__ v) {
    int tid = threadIdx.x;
    int lane = tid & 15;
    int node = blockIdx.x * 16 + (tid >> 4);
    int d = deg[node];
    int c = min(d, MAXDEG);
    float sum = 0.f;
    for (int k = lane; k < c; k += 16) sum += s[bucket[node * MAXDEG + k]];
    sum += __shfl_xor(sum, 1);
    sum += __shfl_xor(sum, 2);
    sum += __shfl_xor(sum, 4);
    sum += __shfl_xor(sum, 8);
    if (lane == 0) {
        float h = sum / (float)max(d, 1) + b2l[0] + t[node];
        v[node] = fmaxf(h, 0.f);
    }
}

// ---------------- K5: z_partial = fc1_W @ v (bias deferred to K6) -----------
// (round-2's fused head regressed 10us -> 102us via per-block __threadfence()
//  forcing cross-XCD L2 ordering. Separate k6 launch is strictly cheaper.)
__global__ void k5_fc1(const float* __restrict__ fc1W, const float* __restrict__ v,
                       float* __restrict__ z) {
    int row = blockIdx.x >> 2;
    int part = blockIdx.x & 3;
    const float4* W4 = (const float4*)(fc1W + row * 50000 + part * 12500);
    const float4* v4 = (const float4*)(v + part * 12500);
    float sum = 0.f;
    for (int i = threadIdx.x; i < 3125; i += 256) {
        float4 w = W4[i], a = v4[i];
        sum += w.x * a.x + w.y * a.y + w.z * a.z + w.w * a.w;
    }
    #pragma unroll
    for (int m = 1; m < 64; m <<= 1) sum += __shfl_xor(sum, m);
    __shared__ float red[4];
    if ((threadIdx.x & 63) == 0) red[threadIdx.x >> 6] = sum;
    __syncthreads();
    if (threadIdx.x == 0) atomicAdd(&z[row], red[0] + red[1] + red[2] + red[3]);
}

// ---------------- K6: pred = fc2_W @ (z + fc1_b) + fc2_b --------------------
__global__ void k6_head(const float* __restrict__ z, const float* __restrict__ fc1b,
                        const float* __restrict__ fc2W, const float* __restrict__ fc2b,
                        float* __restrict__ out) {
    int t = threadIdx.x;  // 256 threads
    float val = (z[t] + fc1b[t]) * fc2W[t];
    #pragma unroll
    for (int m = 1; m < 64; m <<= 1) val += __shfl_xor(val, m);
    __shared__ float red[4];
    if ((t & 63) == 0) red[t >> 6] = val;
    __syncthreads();
    if (t == 0) out[0] = red[0] + red[1] + red[2] + red[3] + fc2b[0];
}

extern "C" void kernel_launch(void* const* d_in, const int* in_sizes, int n_in,
                              void* d_out, int out_size, void* d_ws, size_t ws_size,
                              hipStream_t stream) {
    const float* x    = (const float*)d_in[0];
    const int*   ei   = (const int*)d_in[1];   // jax x64 disabled -> int32
    const float* W1l  = (const float*)d_in[2];
    const float* b1l  = (const float*)d_in[3];
    const float* W1r  = (const float*)d_in[4];
    const float* W2l  = (const float*)d_in[5];
    const float* b2l  = (const float*)d_in[6];
    const float* W2r  = (const float*)d_in[7];
    const float* fc1W = (const float*)d_in[8];
    const float* fc1b = (const float*)d_in[9];
    const float* fc2W = (const float*)d_in[10];
    const float* fc2b = (const float*)d_in[11];
    float* out = (float*)d_out;

    // workspace layout (bytes, 512-aligned)
    char* ws = (char*)d_ws;
    int*            deg    = (int*)           (ws + 0);          //   200,000 B
    float*          z      = (float*)         (ws + 200192);     //     1,024 B
    unsigned short* bucket = (unsigned short*)(ws + 201216);     // 6,400,000 B
    unsigned short* xb     = (unsigned short*)(ws + 6601216);    // 6,400,000 B
    float*          s      = (float*)         (ws + 13001216);   //   200,000 B
    float*          t      = (float*)         (ws + 13201216);   //   200,000 B
    float*          v      = (float*)         (ws + 13401216);   //   200,000 B
    short*          pkhi   = (short*)         (ws + 13601280);   //    32,768 B
    short*          pklo   = (short*)         (ws + 13634048);   //    32,768 B
                                                                 // end 13,666,816

    kW0_init_pack<<<782,  256, 0, stream>>>(x, W1l, W1r, pkhi, pklo, xb, deg, z);
    k1_bucket    <<<K1_BLOCKS, 256, 0, stream>>>(ei, deg, bucket);
    k3_fused     <<<1563, 512, 0, stream>>>(x, xb, deg, bucket, pkhi, pklo, b1l, W2l, W2r, s, t);
    k4_layer2    <<<3125, 256, 0, stream>>>(s, t, deg, bucket, b2l, v);
    k5_fc1       <<<1024, 256, 0, stream>>>(fc1W, v, z);
    k6_head      <<<1,    256, 0, stream>>>(z, fc1b, fc2W, fc2b, out);
}